// Round 2
// baseline (799.553 us; speedup 1.0000x reference)
//
#include <hip/hip_runtime.h>

typedef unsigned short u16;
typedef __attribute__((ext_vector_type(8))) short s16x8;
typedef __attribute__((ext_vector_type(4))) float f32x4;

#define BM 128
#define BN 128
#define BK 32

__device__ __forceinline__ float bf2f(u16 u) {
    union { unsigned int u; float f; } v; v.u = ((unsigned int)u) << 16; return v.f;
}
__device__ __forceinline__ u16 f2bf(float f) {
    union { float f; unsigned int u; } v; v.f = f;
    unsigned int r = v.u + 0x7FFFu + ((v.u >> 16) & 1u);
    return (u16)(r >> 16);
}

// ---------------------------------------------------------------------------
// Detect input dtype. Reads first 4096 u16 of x; if any bf16-interpreted
// magnitude is huge, data is fp32 (low mantissa halves have uniform exponent).
// flag=1 -> fp32 inputs, flag=0 -> bf16 inputs.
// ---------------------------------------------------------------------------
__global__ __launch_bounds__(256) void detect_dtype(const u16* __restrict__ x,
                                                    int* __restrict__ flag) {
    const int t = threadIdx.x;
    float mx = 0.f;
    #pragma unroll
    for (int j = 0; j < 16; ++j) mx = fmaxf(mx, fabsf(bf2f(x[t * 16 + j])));
    #pragma unroll
    for (int off = 32; off; off >>= 1) mx = fmaxf(mx, __shfl_down(mx, off));
    __shared__ float red[4];
    const int lane = t & 63, wave = t >> 6;
    if (lane == 0) red[wave] = mx;
    __syncthreads();
    if (t == 0) {
        float m = fmaxf(fmaxf(red[0], red[1]), fmaxf(red[2], red[3]));
        *flag = (m > 1e4f) ? 1 : 0;
    }
}

__device__ __forceinline__ float load_raw(const void* p, size_t i, int f32) {
    return f32 ? ((const float*)p)[i] : bf2f(((const u16*)p)[i]);
}

// ---------------------------------------------------------------------------
// Per-row int8 fake-quantization from RAW weights -> canonical bf16.
// wq = round(w/scale)*scale, scale = max|row|/127 (>=1e-8)
// ---------------------------------------------------------------------------
__global__ __launch_bounds__(256) void quant_rows(const void* __restrict__ w,
                                                  u16* __restrict__ wq, int L,
                                                  const int* __restrict__ flagp) {
    const int f32 = *flagp;
    const int row = blockIdx.x;
    const int t = threadIdx.x;
    const size_t base = (size_t)row * L;
    float mx = 0.f;
    for (int i = t; i < L; i += 256) mx = fmaxf(mx, fabsf(load_raw(w, base + i, f32)));
    #pragma unroll
    for (int off = 32; off; off >>= 1) mx = fmaxf(mx, __shfl_down(mx, off));
    __shared__ float red[4];
    __shared__ float s_scale;
    const int lane = t & 63, wave = t >> 6;
    if (lane == 0) red[wave] = mx;
    __syncthreads();
    if (t == 0) {
        float m = fmaxf(fmaxf(red[0], red[1]), fmaxf(red[2], red[3]));
        s_scale = fmaxf(m / 127.f, 1e-8f);
    }
    __syncthreads();
    const float scale = s_scale;
    for (int i = t; i < L; i += 256) {
        float v = load_raw(w, base + i, f32);
        wq[base + i] = f2bf(rintf(v / scale) * scale);
    }
}

// ---------------------------------------------------------------------------
// RMSNorm over rows of length 1024 (256 threads x 4 elems).
// IN_RAW=1: x may be fp32 (per flag); IN_RAW=0: x is canonical bf16.
// Norm weight is always a raw input (per flag). Output canonical bf16.
// ---------------------------------------------------------------------------
template <int IN_RAW>
__global__ __launch_bounds__(256) void rmsnorm_k(const void* __restrict__ x,
                                                 const void* __restrict__ w,
                                                 u16* __restrict__ out,
                                                 const int* __restrict__ flagp) {
    const int f32 = *flagp;
    const int row = blockIdx.x;
    const int t = threadIdx.x;
    float x0, x1, x2, x3;
    if (IN_RAW && f32) {
        float4 xv = ((const float4*)x)[(size_t)row * 256 + t];
        x0 = xv.x; x1 = xv.y; x2 = xv.z; x3 = xv.w;
    } else {
        ushort4 xv = *(const ushort4*)((const u16*)x + (size_t)row * 1024 + t * 4);
        x0 = bf2f(xv.x); x1 = bf2f(xv.y); x2 = bf2f(xv.z); x3 = bf2f(xv.w);
    }
    float s = x0 * x0 + x1 * x1 + x2 * x2 + x3 * x3;
    #pragma unroll
    for (int off = 32; off; off >>= 1) s += __shfl_down(s, off);
    __shared__ float red[4];
    __shared__ float s_rs;
    const int lane = t & 63, wave = t >> 6;
    if (lane == 0) red[wave] = s;
    __syncthreads();
    if (t == 0) {
        float tot = red[0] + red[1] + red[2] + red[3];
        s_rs = 1.0f / sqrtf(tot * (1.0f / 1024.0f) + 1e-6f);
    }
    __syncthreads();
    const float rs = s_rs;
    float w0, w1, w2, w3;
    if (f32) {
        float4 wv = ((const float4*)w)[t];
        w0 = wv.x; w1 = wv.y; w2 = wv.z; w3 = wv.w;
    } else {
        ushort4 wv = *(const ushort4*)((const u16*)w + t * 4);
        w0 = bf2f(wv.x); w1 = bf2f(wv.y); w2 = bf2f(wv.z); w3 = bf2f(wv.w);
    }
    ushort4 o;
    o.x = f2bf(bf2f(f2bf(x0 * rs)) * w0);
    o.y = f2bf(bf2f(f2bf(x1 * rs)) * w1);
    o.z = f2bf(bf2f(f2bf(x2 * rs)) * w2);
    o.w = f2bf(bf2f(f2bf(x3 * rs)) * w3);
    *(ushort4*)(out + (size_t)row * 1024 + t * 4) = o;
}

// ---------------------------------------------------------------------------
// Causal geometric-filter scan + SiLU gate, IN-PLACE into the gate half.
// y[t] = r*y[t-1] + s[t]; qkv[.., 1024+c] <- y * silu(gate).  r = exp(-0.1).
// qkv is (B*T, 2048) bf16: signal cols [0,1024), gate cols [1024,2048).
// Chunked over T with 384-step warm-up (r^384 ~ 2e-17). Warm-up reads only
// the signal half, which is never overwritten -> no inter-block race.
// grid: (colgroup=4, chunk=16, b=4), block 256.
// ---------------------------------------------------------------------------
__global__ __launch_bounds__(256) void scan_silu(u16* __restrict__ qkv) {
    const int c = blockIdx.x * 256 + threadIdx.x;   // 0..1023
    const int chunk = blockIdx.y;                   // 0..15
    const int b = blockIdx.z;                       // 0..3
    const int t0 = chunk * 256;
    const int ts = (t0 >= 384) ? (t0 - 384) : 0;
    const float r = 0.90483741803595957f;           // exp(-0.1)
    const size_t base = (size_t)b * 4096 * 2048 + c;
    float y = 0.f;
    for (int tt = ts; tt < t0; ++tt) {
        y = y * r + bf2f(qkv[base + (size_t)tt * 2048]);
    }
    for (int tt = t0; tt < t0 + 256; ++tt) {
        const size_t idx = base + (size_t)tt * 2048;
        y = y * r + bf2f(qkv[idx]);
        float g = bf2f(qkv[idx + 1024]);
        float sg = g / (1.f + expf(-g));
        qkv[idx + 1024] = f2bf(y * sg);
    }
}

// ---------------------------------------------------------------------------
// bf16 MFMA GEMM: C(MxN) = A(MxK,lda) @ B(NxK)^T  [+ epilogue]
// EPI: 0 = none, 1 = add RES, 2 = exact GELU
// RES/C may be raw (fp32 when flag set) or canonical bf16.
// block 256 (4 waves), tile 128x128, BK=32, 16x16x32 MFMA.
// ---------------------------------------------------------------------------
template <int EPI>
__global__ __launch_bounds__(256) void gemm_bt(const u16* __restrict__ A, int lda,
                                               const u16* __restrict__ B,
                                               const void* __restrict__ RES, int res_raw,
                                               void* __restrict__ C, int c_raw,
                                               int M, int N, int K,
                                               const int* __restrict__ flagp) {
    const int f32 = *flagp;
    __shared__ u16 As[BM * BK];
    __shared__ u16 Bs[BN * BK];
    const int t = threadIdx.x;
    const int lane = t & 63, wave = t >> 6;
    const int wm = wave >> 1, wn = wave & 1;
    const int lr = lane & 15, quad = lane >> 4;
    const int m0 = blockIdx.y * BM, n0 = blockIdx.x * BN;

    // staging: thread t loads 32 contiguous bytes (2x16B) of one tile row
    const int srow = t >> 1;            // 0..127
    const int scol = (t & 1) * 16;      // element col 0 or 16
    const size_t a_base = (size_t)(m0 + srow) * lda + scol;
    const size_t b_base = (size_t)(n0 + srow) * K + scol;

    f32x4 acc[4][4];
    #pragma unroll
    for (int i = 0; i < 4; ++i)
        #pragma unroll
        for (int j = 0; j < 4; ++j) acc[i][j] = (f32x4){0.f, 0.f, 0.f, 0.f};

    for (int k0 = 0; k0 < K; k0 += BK) {
        s16x8 a0 = *(const s16x8*)(A + a_base + k0);
        s16x8 a1 = *(const s16x8*)(A + a_base + k0 + 8);
        s16x8 b0 = *(const s16x8*)(B + b_base + k0);
        s16x8 b1 = *(const s16x8*)(B + b_base + k0 + 8);
        __syncthreads();
        *(s16x8*)&As[srow * BK + scol]     = a0;
        *(s16x8*)&As[srow * BK + scol + 8] = a1;
        *(s16x8*)&Bs[srow * BK + scol]     = b0;
        *(s16x8*)&Bs[srow * BK + scol + 8] = b1;
        __syncthreads();
        s16x8 af[4], bfr[4];
        #pragma unroll
        for (int i = 0; i < 4; ++i)
            af[i] = *(const s16x8*)&As[(wm * 64 + i * 16 + lr) * BK + quad * 8];
        #pragma unroll
        for (int j = 0; j < 4; ++j)
            bfr[j] = *(const s16x8*)&Bs[(wn * 64 + j * 16 + lr) * BK + quad * 8];
        #pragma unroll
        for (int i = 0; i < 4; ++i)
            #pragma unroll
            for (int j = 0; j < 4; ++j)
                acc[i][j] = __builtin_amdgcn_mfma_f32_16x16x32_bf16(
                    af[i], bfr[j], acc[i][j], 0, 0, 0);
    }

    // epilogue: C/D layout col=lane&15, row=quad*4+reg
    #pragma unroll
    for (int i = 0; i < 4; ++i) {
        #pragma unroll
        for (int j = 0; j < 4; ++j) {
            #pragma unroll
            for (int r = 0; r < 4; ++r) {
                int gm = m0 + wm * 64 + i * 16 + quad * 4 + r;
                int gn = n0 + wn * 64 + j * 16 + lr;
                size_t idx = (size_t)gm * N + gn;
                float v = acc[i][j][r];
                if (EPI == 1) {
                    float rv = (res_raw && f32) ? ((const float*)RES)[idx]
                                                : bf2f(((const u16*)RES)[idx]);
                    v += rv;
                }
                if (EPI == 2) v = 0.5f * v * (1.0f + erff(v * 0.70710678118654752f));
                if (c_raw && f32) ((float*)C)[idx] = v;
                else              ((u16*)C)[idx] = f2bf(v);
            }
        }
    }
}

// ---------------------------------------------------------------------------
extern "C" void kernel_launch(void* const* d_in, const int* in_sizes, int n_in,
                              void* d_out, int out_size, void* d_ws, size_t ws_size,
                              hipStream_t stream) {
    const void* x    = d_in[0];   // (4,4096,1024)  fp32 or bf16
    const void* n1w  = d_in[1];   // (1024,)
    const void* n2w  = d_in[2];   // (1024,)
    const void* w_in = d_in[3];   // (2048,1024)
    const void* w_o  = d_in[4];   // (1024,1024)
    const void* w_mi = d_in[5];   // (2048,1024)
    const void* w_mo = d_in[6];   // (1024,2048)
    // d_in[7] fixed_filter: exp(-0.1*t) geometric -> IIR scan, unused

    char* ws = (char*)d_ws;
    int* flag  = (int*)(ws + 0);                 // 256 B reserved
    u16* wq_in = (u16*)(ws + 256);               // 4 MB
    u16* wq_o  = (u16*)(ws + 256 + 4194304);     // 2 MB
    u16* wq_mi = (u16*)(ws + 256 + 6291456);     // 4 MB
    u16* wq_mo = (u16*)(ws + 256 + 10485760);    // 4 MB
    u16* hbuf  = (u16*)(ws + 256 + 14680064);    // 32 MB (h / h2, bf16)
    u16* qkv   = (u16*)(ws + 256 + 48234496);    // 64 MB (qkv / m, bf16)
    u16* x2b   = (u16*)(ws + 256 + 115343360);   // 32 MB (x2, bf16)

    detect_dtype<<<1, 256, 0, stream>>>((const u16*)x, flag);

    // fake-int8 quantize the four weight matrices -> canonical bf16
    quant_rows<<<2048, 256, 0, stream>>>(w_in, wq_in, 1024, flag);
    quant_rows<<<1024, 256, 0, stream>>>(w_o,  wq_o,  1024, flag);
    quant_rows<<<2048, 256, 0, stream>>>(w_mi, wq_mi, 1024, flag);
    quant_rows<<<1024, 256, 0, stream>>>(w_mo, wq_mo, 2048, flag);

    // h = rmsnorm(x, n1w)
    rmsnorm_k<1><<<16384, 256, 0, stream>>>(x, n1w, hbuf, flag);
    // qkv = h @ wq_in^T   (16384 x 2048)
    gemm_bt<0><<<dim3(16, 128), 256, 0, stream>>>(hbuf, 1024, wq_in,
                                                  nullptr, 0, qkv, 0,
                                                  16384, 2048, 1024, flag);
    // gate half of qkv <- causal-conv(signal) * silu(gate), in place
    scan_silu<<<dim3(4, 16, 4), 256, 0, stream>>>(qkv);
    // x2 = x + attn @ wq_o^T   (attn = qkv gate half, lda=2048)
    gemm_bt<1><<<dim3(8, 128), 256, 0, stream>>>(qkv + 1024, 2048, wq_o,
                                                 x, 1, x2b, 0,
                                                 16384, 1024, 1024, flag);
    // h2 = rmsnorm(x2, n2w)
    rmsnorm_k<0><<<16384, 256, 0, stream>>>(x2b, n2w, hbuf, flag);
    // m = gelu(h2 @ wq_mi^T)  (16384 x 2048), overwrite qkv
    gemm_bt<2><<<dim3(16, 128), 256, 0, stream>>>(hbuf, 1024, wq_mi,
                                                  nullptr, 0, qkv, 0,
                                                  16384, 2048, 1024, flag);
    // out = x2 + m @ wq_mo^T  -> d_out in the detected dtype
    gemm_bt<1><<<dim3(8, 128), 256, 0, stream>>>(qkv, 2048, wq_mo,
                                                 x2b, 0, d_out, 1,
                                                 16384, 1024, 2048, flag);
}

// Round 3
// 732.789 us; speedup vs baseline: 1.0911x; 1.0911x over previous
//
#include <hip/hip_runtime.h>

typedef unsigned short u16;
typedef __attribute__((ext_vector_type(8))) short s16x8;
typedef __attribute__((ext_vector_type(4))) float f32x4;

#define BM 128
#define BN 128
#define BK 32

__device__ __forceinline__ float bf2f(u16 u) {
    union { unsigned int u; float f; } v; v.u = ((unsigned int)u) << 16; return v.f;
}
__device__ __forceinline__ u16 f2bf(float f) {
    union { float f; unsigned int u; } v; v.f = f;
    unsigned int r = v.u + 0x7FFFu + ((v.u >> 16) & 1u);
    return (u16)(r >> 16);
}

// async 16B/lane global->LDS copy. lds base must be wave-uniform; HW writes
// lane l's 16 bytes at base + l*16.
__device__ __forceinline__ void async16(const u16* g, u16* l) {
    __builtin_amdgcn_global_load_lds(
        (const __attribute__((address_space(1))) void*)g,
        (__attribute__((address_space(3))) void*)l,
        16, 0, 0);
}

// ---------------------------------------------------------------------------
// Detect input dtype. flag=1 -> fp32 inputs, flag=0 -> bf16 inputs.
// ---------------------------------------------------------------------------
__global__ __launch_bounds__(256) void detect_dtype(const u16* __restrict__ x,
                                                    int* __restrict__ flag) {
    const int t = threadIdx.x;
    float mx = 0.f;
    #pragma unroll
    for (int j = 0; j < 16; ++j) mx = fmaxf(mx, fabsf(bf2f(x[t * 16 + j])));
    #pragma unroll
    for (int off = 32; off; off >>= 1) mx = fmaxf(mx, __shfl_down(mx, off));
    __shared__ float red[4];
    const int lane = t & 63, wave = t >> 6;
    if (lane == 0) red[wave] = mx;
    __syncthreads();
    if (t == 0) {
        float m = fmaxf(fmaxf(red[0], red[1]), fmaxf(red[2], red[3]));
        *flag = (m > 1e4f) ? 1 : 0;
    }
}

__device__ __forceinline__ float load_raw(const void* p, size_t i, int f32) {
    return f32 ? ((const float*)p)[i] : bf2f(((const u16*)p)[i]);
}

// ---------------------------------------------------------------------------
// Per-row int8 fake-quantization from RAW weights -> canonical bf16.
// ---------------------------------------------------------------------------
__global__ __launch_bounds__(256) void quant_rows(const void* __restrict__ w,
                                                  u16* __restrict__ wq, int L,
                                                  const int* __restrict__ flagp) {
    const int f32 = *flagp;
    const int row = blockIdx.x;
    const int t = threadIdx.x;
    const size_t base = (size_t)row * L;
    float mx = 0.f;
    for (int i = t; i < L; i += 256) mx = fmaxf(mx, fabsf(load_raw(w, base + i, f32)));
    #pragma unroll
    for (int off = 32; off; off >>= 1) mx = fmaxf(mx, __shfl_down(mx, off));
    __shared__ float red[4];
    __shared__ float s_scale;
    const int lane = t & 63, wave = t >> 6;
    if (lane == 0) red[wave] = mx;
    __syncthreads();
    if (t == 0) {
        float m = fmaxf(fmaxf(red[0], red[1]), fmaxf(red[2], red[3]));
        s_scale = fmaxf(m / 127.f, 1e-8f);
    }
    __syncthreads();
    const float scale = s_scale;
    for (int i = t; i < L; i += 256) {
        float v = load_raw(w, base + i, f32);
        wq[base + i] = f2bf(rintf(v / scale) * scale);
    }
}

// ---------------------------------------------------------------------------
// RMSNorm over rows of length 1024 (256 threads x 4 elems).
// ---------------------------------------------------------------------------
template <int IN_RAW>
__global__ __launch_bounds__(256) void rmsnorm_k(const void* __restrict__ x,
                                                 const void* __restrict__ w,
                                                 u16* __restrict__ out,
                                                 const int* __restrict__ flagp) {
    const int f32 = *flagp;
    const int row = blockIdx.x;
    const int t = threadIdx.x;
    float x0, x1, x2, x3;
    if (IN_RAW && f32) {
        float4 xv = ((const float4*)x)[(size_t)row * 256 + t];
        x0 = xv.x; x1 = xv.y; x2 = xv.z; x3 = xv.w;
    } else {
        ushort4 xv = *(const ushort4*)((const u16*)x + (size_t)row * 1024 + t * 4);
        x0 = bf2f(xv.x); x1 = bf2f(xv.y); x2 = bf2f(xv.z); x3 = bf2f(xv.w);
    }
    float s = x0 * x0 + x1 * x1 + x2 * x2 + x3 * x3;
    #pragma unroll
    for (int off = 32; off; off >>= 1) s += __shfl_down(s, off);
    __shared__ float red[4];
    __shared__ float s_rs;
    const int lane = t & 63, wave = t >> 6;
    if (lane == 0) red[wave] = s;
    __syncthreads();
    if (t == 0) {
        float tot = red[0] + red[1] + red[2] + red[3];
        s_rs = 1.0f / sqrtf(tot * (1.0f / 1024.0f) + 1e-6f);
    }
    __syncthreads();
    const float rs = s_rs;
    float w0, w1, w2, w3;
    if (f32) {
        float4 wv = ((const float4*)w)[t];
        w0 = wv.x; w1 = wv.y; w2 = wv.z; w3 = wv.w;
    } else {
        ushort4 wv = *(const ushort4*)((const u16*)w + t * 4);
        w0 = bf2f(wv.x); w1 = bf2f(wv.y); w2 = bf2f(wv.z); w3 = bf2f(wv.w);
    }
    ushort4 o;
    o.x = f2bf(bf2f(f2bf(x0 * rs)) * w0);
    o.y = f2bf(bf2f(f2bf(x1 * rs)) * w1);
    o.z = f2bf(bf2f(f2bf(x2 * rs)) * w2);
    o.w = f2bf(bf2f(f2bf(x3 * rs)) * w3);
    *(ushort4*)(out + (size_t)row * 1024 + t * 4) = o;
}

// ---------------------------------------------------------------------------
// Causal geometric-filter scan + SiLU gate, in-place into the gate half.
// ---------------------------------------------------------------------------
__global__ __launch_bounds__(256) void scan_silu(u16* __restrict__ qkv) {
    const int c = blockIdx.x * 256 + threadIdx.x;   // 0..1023
    const int chunk = blockIdx.y;                   // 0..15
    const int b = blockIdx.z;                       // 0..3
    const int t0 = chunk * 256;
    const int ts = (t0 >= 256) ? (t0 - 256) : 0;    // r^256 ~ 7e-12
    const float r = 0.90483741803595957f;           // exp(-0.1)
    const size_t base = (size_t)b * 4096 * 2048 + c;
    float y = 0.f;
    for (int tt = ts; tt < t0; ++tt) {
        y = y * r + bf2f(qkv[base + (size_t)tt * 2048]);
    }
    for (int tt = t0; tt < t0 + 256; ++tt) {
        const size_t idx = base + (size_t)tt * 2048;
        y = y * r + bf2f(qkv[idx]);
        float g = bf2f(qkv[idx + 1024]);
        float sg = g / (1.f + expf(-g));
        qkv[idx + 1024] = f2bf(y * sg);
    }
}

// ---------------------------------------------------------------------------
// bf16 MFMA GEMM: C(MxN) = A(MxK,lda) @ B(NxK)^T  [+ epilogue]
// EPI: 0 = none, 1 = add RES, 2 = exact GELU
// m97 structure: global_load_lds width-16 staging, 2-barrier K-loop.
// ---------------------------------------------------------------------------
template <int EPI>
__global__ __launch_bounds__(256) void gemm_bt(const u16* __restrict__ A, int lda,
                                               const u16* __restrict__ B,
                                               const void* __restrict__ RES, int res_raw,
                                               void* __restrict__ C, int c_raw,
                                               int M, int N, int K,
                                               const int* __restrict__ flagp) {
    const int f32 = *flagp;
    __shared__ u16 As[BM * BK];
    __shared__ u16 Bs[BN * BK];
    const int t = threadIdx.x;
    const int lane = t & 63, wave = t >> 6;
    const int wm = wave >> 1, wn = wave & 1;
    const int lr = lane & 15, quad = lane >> 4;
    const int m0 = blockIdx.y * BM, n0 = blockIdx.x * BN;

    // async staging: instruction i (0/1), wave w, lane l stages tile row
    // i*64 + w*16 + (l>>2), col elements (l&3)*8 .. +8.  LDS dst is
    // wave-uniform base; HW scatters lane l at base + l*16 bytes.
    const int srow = wave * 16 + (lane >> 2);
    const int scol = (lane & 3) * 8;
    const u16* Ag0 = A + (size_t)(m0 + srow) * lda + scol;
    const u16* Ag1 = A + (size_t)(m0 + srow + 64) * lda + scol;
    const u16* Bg0 = B + (size_t)(n0 + srow) * K + scol;
    const u16* Bg1 = B + (size_t)(n0 + srow + 64) * K + scol;
    u16* Al0 = &As[(wave * 16) * BK];
    u16* Al1 = &As[(64 + wave * 16) * BK];
    u16* Bl0 = &Bs[(wave * 16) * BK];
    u16* Bl1 = &Bs[(64 + wave * 16) * BK];

    f32x4 acc[4][4];
    #pragma unroll
    for (int i = 0; i < 4; ++i)
        #pragma unroll
        for (int j = 0; j < 4; ++j) acc[i][j] = (f32x4){0.f, 0.f, 0.f, 0.f};

    for (int k0 = 0; k0 < K; k0 += BK) {
        __syncthreads();                    // prior ds_reads complete
        async16(Ag0 + k0, Al0);
        async16(Ag1 + k0, Al1);
        async16(Bg0 + k0, Bl0);
        async16(Bg1 + k0, Bl1);
        __syncthreads();                    // drains vmcnt -> LDS valid
        s16x8 af[4], bfr[4];
        #pragma unroll
        for (int i = 0; i < 4; ++i)
            af[i] = *(const s16x8*)&As[(wm * 64 + i * 16 + lr) * BK + quad * 8];
        #pragma unroll
        for (int j = 0; j < 4; ++j)
            bfr[j] = *(const s16x8*)&Bs[(wn * 64 + j * 16 + lr) * BK + quad * 8];
        #pragma unroll
        for (int i = 0; i < 4; ++i)
            #pragma unroll
            for (int j = 0; j < 4; ++j)
                acc[i][j] = __builtin_amdgcn_mfma_f32_16x16x32_bf16(
                    af[i], bfr[j], acc[i][j], 0, 0, 0);
    }

    // epilogue: C/D layout col=lane&15, row=quad*4+reg
    #pragma unroll
    for (int i = 0; i < 4; ++i) {
        #pragma unroll
        for (int j = 0; j < 4; ++j) {
            #pragma unroll
            for (int r = 0; r < 4; ++r) {
                int gm = m0 + wm * 64 + i * 16 + quad * 4 + r;
                int gn = n0 + wn * 64 + j * 16 + lr;
                size_t idx = (size_t)gm * N + gn;
                float v = acc[i][j][r];
                if (EPI == 1) {
                    float rv = (res_raw && f32) ? ((const float*)RES)[idx]
                                                : bf2f(((const u16*)RES)[idx]);
                    v += rv;
                }
                if (EPI == 2) v = 0.5f * v * (1.0f + erff(v * 0.70710678118654752f));
                if (c_raw && f32) ((float*)C)[idx] = v;
                else              ((u16*)C)[idx] = f2bf(v);
            }
        }
    }
}

// ---------------------------------------------------------------------------
extern "C" void kernel_launch(void* const* d_in, const int* in_sizes, int n_in,
                              void* d_out, int out_size, void* d_ws, size_t ws_size,
                              hipStream_t stream) {
    const void* x    = d_in[0];   // (4,4096,1024)  fp32 or bf16
    const void* n1w  = d_in[1];   // (1024,)
    const void* n2w  = d_in[2];   // (1024,)
    const void* w_in = d_in[3];   // (2048,1024)
    const void* w_o  = d_in[4];   // (1024,1024)
    const void* w_mi = d_in[5];   // (2048,1024)
    const void* w_mo = d_in[6];   // (1024,2048)
    // d_in[7] fixed_filter: exp(-0.1*t) geometric -> IIR scan, unused

    char* ws = (char*)d_ws;
    int* flag  = (int*)(ws + 0);                 // 256 B reserved
    u16* wq_in = (u16*)(ws + 256);               // 4 MB
    u16* wq_o  = (u16*)(ws + 256 + 4194304);     // 2 MB
    u16* wq_mi = (u16*)(ws + 256 + 6291456);     // 4 MB
    u16* wq_mo = (u16*)(ws + 256 + 10485760);    // 4 MB
    u16* hbuf  = (u16*)(ws + 256 + 14680064);    // 32 MB (h / h2, bf16)
    u16* qkv   = (u16*)(ws + 256 + 48234496);    // 64 MB (qkv / m, bf16)
    u16* x2b   = (u16*)(ws + 256 + 115343360);   // 32 MB (x2, bf16)

    detect_dtype<<<1, 256, 0, stream>>>((const u16*)x, flag);

    quant_rows<<<2048, 256, 0, stream>>>(w_in, wq_in, 1024, flag);
    quant_rows<<<1024, 256, 0, stream>>>(w_o,  wq_o,  1024, flag);
    quant_rows<<<2048, 256, 0, stream>>>(w_mi, wq_mi, 1024, flag);
    quant_rows<<<1024, 256, 0, stream>>>(w_mo, wq_mo, 2048, flag);

    // h = rmsnorm(x, n1w)
    rmsnorm_k<1><<<16384, 256, 0, stream>>>(x, n1w, hbuf, flag);
    // qkv = h @ wq_in^T   (16384 x 2048)
    gemm_bt<0><<<dim3(16, 128), 256, 0, stream>>>(hbuf, 1024, wq_in,
                                                  nullptr, 0, qkv, 0,
                                                  16384, 2048, 1024, flag);
    // gate half of qkv <- causal-conv(signal) * silu(gate), in place
    scan_silu<<<dim3(4, 16, 4), 256, 0, stream>>>(qkv);
    // x2 = x + attn @ wq_o^T   (attn = qkv gate half, lda=2048)
    gemm_bt<1><<<dim3(8, 128), 256, 0, stream>>>(qkv + 1024, 2048, wq_o,
                                                 x, 1, x2b, 0,
                                                 16384, 1024, 1024, flag);
    // h2 = rmsnorm(x2, n2w)
    rmsnorm_k<0><<<16384, 256, 0, stream>>>(x2b, n2w, hbuf, flag);
    // m = gelu(h2 @ wq_mi^T)  (16384 x 2048), overwrite qkv
    gemm_bt<2><<<dim3(16, 128), 256, 0, stream>>>(hbuf, 1024, wq_mi,
                                                  nullptr, 0, qkv, 0,
                                                  16384, 2048, 1024, flag);
    // out = x2 + m @ wq_mo^T  -> d_out in the detected dtype
    gemm_bt<1><<<dim3(8, 128), 256, 0, stream>>>(qkv, 2048, wq_mo,
                                                 x2b, 0, d_out, 1,
                                                 16384, 1024, 2048, flag);
}

// Round 4
// 673.711 us; speedup vs baseline: 1.1868x; 1.0877x over previous
//
#include <hip/hip_runtime.h>

typedef unsigned short u16;
typedef __attribute__((ext_vector_type(8))) short s16x8;
typedef __attribute__((ext_vector_type(4))) float f32x4;

#define BM 128
#define BN 128

__device__ __forceinline__ float bf2f(u16 u) {
    union { unsigned int u; float f; } v; v.u = ((unsigned int)u) << 16; return v.f;
}
__device__ __forceinline__ u16 f2bf(float f) {
    union { float f; unsigned int u; } v; v.f = f;
    unsigned int r = v.u + 0x7FFFu + ((v.u >> 16) & 1u);
    return (u16)(r >> 16);
}

// async 16B/lane global->LDS copy. lds base must be wave-uniform; HW writes
// lane l's 16 bytes at base + l*16.
__device__ __forceinline__ void async16(const u16* g, u16* l) {
    __builtin_amdgcn_global_load_lds(
        (const __attribute__((address_space(1))) void*)g,
        (__attribute__((address_space(3))) void*)l,
        16, 0, 0);
}

// ---------------------------------------------------------------------------
// Detect input dtype. flag=1 -> fp32 inputs, flag=0 -> bf16 inputs.
// ---------------------------------------------------------------------------
__global__ __launch_bounds__(256) void detect_dtype(const u16* __restrict__ x,
                                                    int* __restrict__ flag) {
    const int t = threadIdx.x;
    float mx = 0.f;
    #pragma unroll
    for (int j = 0; j < 16; ++j) mx = fmaxf(mx, fabsf(bf2f(x[t * 16 + j])));
    #pragma unroll
    for (int off = 32; off; off >>= 1) mx = fmaxf(mx, __shfl_down(mx, off));
    __shared__ float red[4];
    const int lane = t & 63, wave = t >> 6;
    if (lane == 0) red[wave] = mx;
    __syncthreads();
    if (t == 0) {
        float m = fmaxf(fmaxf(red[0], red[1]), fmaxf(red[2], red[3]));
        *flag = (m > 1e4f) ? 1 : 0;
    }
}

__device__ __forceinline__ float load_raw(const void* p, size_t i, int f32) {
    return f32 ? ((const float*)p)[i] : bf2f(((const u16*)p)[i]);
}

// ---------------------------------------------------------------------------
// Per-row int8 fake-quantization from RAW weights -> canonical bf16.
// ---------------------------------------------------------------------------
__global__ __launch_bounds__(256) void quant_rows(const void* __restrict__ w,
                                                  u16* __restrict__ wq, int L,
                                                  const int* __restrict__ flagp) {
    const int f32 = *flagp;
    const int row = blockIdx.x;
    const int t = threadIdx.x;
    const size_t base = (size_t)row * L;
    float mx = 0.f;
    for (int i = t; i < L; i += 256) mx = fmaxf(mx, fabsf(load_raw(w, base + i, f32)));
    #pragma unroll
    for (int off = 32; off; off >>= 1) mx = fmaxf(mx, __shfl_down(mx, off));
    __shared__ float red[4];
    __shared__ float s_scale;
    const int lane = t & 63, wave = t >> 6;
    if (lane == 0) red[wave] = mx;
    __syncthreads();
    if (t == 0) {
        float m = fmaxf(fmaxf(red[0], red[1]), fmaxf(red[2], red[3]));
        s_scale = fmaxf(m / 127.f, 1e-8f);
    }
    __syncthreads();
    const float scale = s_scale;
    for (int i = t; i < L; i += 256) {
        float v = load_raw(w, base + i, f32);
        wq[base + i] = f2bf(rintf(v / scale) * scale);
    }
}

// ---------------------------------------------------------------------------
// RMSNorm over rows of length 1024 (256 threads x 4 elems).
// ---------------------------------------------------------------------------
template <int IN_RAW>
__global__ __launch_bounds__(256) void rmsnorm_k(const void* __restrict__ x,
                                                 const void* __restrict__ w,
                                                 u16* __restrict__ out,
                                                 const int* __restrict__ flagp) {
    const int f32 = *flagp;
    const int row = blockIdx.x;
    const int t = threadIdx.x;
    float x0, x1, x2, x3;
    if (IN_RAW && f32) {
        float4 xv = ((const float4*)x)[(size_t)row * 256 + t];
        x0 = xv.x; x1 = xv.y; x2 = xv.z; x3 = xv.w;
    } else {
        ushort4 xv = *(const ushort4*)((const u16*)x + (size_t)row * 1024 + t * 4);
        x0 = bf2f(xv.x); x1 = bf2f(xv.y); x2 = bf2f(xv.z); x3 = bf2f(xv.w);
    }
    float s = x0 * x0 + x1 * x1 + x2 * x2 + x3 * x3;
    #pragma unroll
    for (int off = 32; off; off >>= 1) s += __shfl_down(s, off);
    __shared__ float red[4];
    __shared__ float s_rs;
    const int lane = t & 63, wave = t >> 6;
    if (lane == 0) red[wave] = s;
    __syncthreads();
    if (t == 0) {
        float tot = red[0] + red[1] + red[2] + red[3];
        s_rs = 1.0f / sqrtf(tot * (1.0f / 1024.0f) + 1e-6f);
    }
    __syncthreads();
    const float rs = s_rs;
    float w0, w1, w2, w3;
    if (f32) {
        float4 wv = ((const float4*)w)[t];
        w0 = wv.x; w1 = wv.y; w2 = wv.z; w3 = wv.w;
    } else {
        ushort4 wv = *(const ushort4*)((const u16*)w + t * 4);
        w0 = bf2f(wv.x); w1 = bf2f(wv.y); w2 = bf2f(wv.z); w3 = bf2f(wv.w);
    }
    ushort4 o;
    o.x = f2bf(bf2f(f2bf(x0 * rs)) * w0);
    o.y = f2bf(bf2f(f2bf(x1 * rs)) * w1);
    o.z = f2bf(bf2f(f2bf(x2 * rs)) * w2);
    o.w = f2bf(bf2f(f2bf(x3 * rs)) * w3);
    *(ushort4*)(out + (size_t)row * 1024 + t * 4) = o;
}

// ---------------------------------------------------------------------------
// Causal geometric-filter scan + SiLU gate, in-place into the gate half.
// ---------------------------------------------------------------------------
__global__ __launch_bounds__(256) void scan_silu(u16* __restrict__ qkv) {
    const int c = blockIdx.x * 256 + threadIdx.x;   // 0..1023
    const int chunk = blockIdx.y;                   // 0..15
    const int b = blockIdx.z;                       // 0..3
    const int t0 = chunk * 256;
    const int ts = (t0 >= 256) ? (t0 - 256) : 0;    // r^256 ~ 7e-12
    const float r = 0.90483741803595957f;           // exp(-0.1)
    const size_t base = (size_t)b * 4096 * 2048 + c;
    float y = 0.f;
    for (int tt = ts; tt < t0; ++tt) {
        y = y * r + bf2f(qkv[base + (size_t)tt * 2048]);
    }
    for (int tt = t0; tt < t0 + 256; ++tt) {
        const size_t idx = base + (size_t)tt * 2048;
        y = y * r + bf2f(qkv[idx]);
        float g = bf2f(qkv[idx + 1024]);
        float sg = g / (1.f + expf(-g));
        qkv[idx + 1024] = f2bf(y * sg);
    }
}

// ---------------------------------------------------------------------------
// bf16 MFMA GEMM: C(MxN) = A(MxK,lda) @ B(NxK)^T  [+ epilogue]
// EPI: 0 = none, 1 = add RES, 2 = exact GELU
// m97-style async staging, BK=64 as two 32-k sub-buffers (32 KB LDS),
// XCD-aware 1-D block swizzle: all n-blocks of an m-row on one XCD so the
// B matrix stays L2-resident and each A row-tile is fetched once per XCD.
// ---------------------------------------------------------------------------
template <int EPI>
__global__ __launch_bounds__(256) void gemm_bt(const u16* __restrict__ A, int lda,
                                               const u16* __restrict__ B,
                                               const void* __restrict__ RES, int res_raw,
                                               void* __restrict__ C, int c_raw,
                                               int M, int N, int K,
                                               const int* __restrict__ flagp) {
    const int f32 = *flagp;
    __shared__ u16 As0[BM * 32], As1[BM * 32];
    __shared__ u16 Bs0[BN * 32], Bs1[BN * 32];
    const int t = threadIdx.x;
    const int lane = t & 63, wave = t >> 6;
    const int wm = wave >> 1, wn = wave & 1;
    const int lr = lane & 15, quad = lane >> 4;

    // XCD-aware swizzle: d%8 -> XCD (dispatch round-robin heuristic).
    const int NT = N >> 7;                  // n-tiles
    const int d = blockIdx.x;
    const int xcd = d & 7;
    const int s = d >> 3;
    const int m0 = ((s / NT) * 8 + xcd) * BM;
    const int n0 = (s % NT) * BN;

    // staging: wave w, lane l stages tile row i*64 + w*16 + (l>>2),
    // cols (l&3)*8..+8 of a 32-k slice. LDS dst wave-uniform.
    const int srow = wave * 16 + (lane >> 2);
    const int scol = (lane & 3) * 8;
    const u16* Ag0 = A + (size_t)(m0 + srow) * lda + scol;
    const u16* Ag1 = A + (size_t)(m0 + srow + 64) * lda + scol;
    const u16* Bg0 = B + (size_t)(n0 + srow) * K + scol;
    const u16* Bg1 = B + (size_t)(n0 + srow + 64) * K + scol;
    u16* Al0a = &As0[(wave * 16) * 32];
    u16* Al1a = &As0[(64 + wave * 16) * 32];
    u16* Bl0a = &Bs0[(wave * 16) * 32];
    u16* Bl1a = &Bs0[(64 + wave * 16) * 32];
    u16* Al0b = &As1[(wave * 16) * 32];
    u16* Al1b = &As1[(64 + wave * 16) * 32];
    u16* Bl0b = &Bs1[(wave * 16) * 32];
    u16* Bl1b = &Bs1[(64 + wave * 16) * 32];

    f32x4 acc[4][4];
    #pragma unroll
    for (int i = 0; i < 4; ++i)
        #pragma unroll
        for (int j = 0; j < 4; ++j) acc[i][j] = (f32x4){0.f, 0.f, 0.f, 0.f};

    for (int k0 = 0; k0 < K; k0 += 64) {
        __syncthreads();                    // prior ds_reads complete
        async16(Ag0 + k0, Al0a);
        async16(Ag1 + k0, Al1a);
        async16(Bg0 + k0, Bl0a);
        async16(Bg1 + k0, Bl1a);
        async16(Ag0 + k0 + 32, Al0b);
        async16(Ag1 + k0 + 32, Al1b);
        async16(Bg0 + k0 + 32, Bl0b);
        async16(Bg1 + k0 + 32, Bl1b);
        __syncthreads();                    // drains vmcnt -> LDS valid
        #pragma unroll
        for (int sl = 0; sl < 2; ++sl) {
            const u16* Asl = sl ? As1 : As0;
            const u16* Bsl = sl ? Bs1 : Bs0;
            s16x8 af[4], bfr[4];
            #pragma unroll
            for (int i = 0; i < 4; ++i)
                af[i] = *(const s16x8*)&Asl[(wm * 64 + i * 16 + lr) * 32 + quad * 8];
            #pragma unroll
            for (int j = 0; j < 4; ++j)
                bfr[j] = *(const s16x8*)&Bsl[(wn * 64 + j * 16 + lr) * 32 + quad * 8];
            #pragma unroll
            for (int i = 0; i < 4; ++i)
                #pragma unroll
                for (int j = 0; j < 4; ++j)
                    acc[i][j] = __builtin_amdgcn_mfma_f32_16x16x32_bf16(
                        af[i], bfr[j], acc[i][j], 0, 0, 0);
        }
    }

    // epilogue: C/D layout col=lane&15, row=quad*4+reg
    #pragma unroll
    for (int i = 0; i < 4; ++i) {
        #pragma unroll
        for (int j = 0; j < 4; ++j) {
            #pragma unroll
            for (int r = 0; r < 4; ++r) {
                int gm = m0 + wm * 64 + i * 16 + quad * 4 + r;
                int gn = n0 + wn * 64 + j * 16 + lr;
                size_t idx = (size_t)gm * N + gn;
                float v = acc[i][j][r];
                if (EPI == 1) {
                    float rv = (res_raw && f32) ? ((const float*)RES)[idx]
                                                : bf2f(((const u16*)RES)[idx]);
                    v += rv;
                }
                if (EPI == 2) v = 0.5f * v * (1.0f + erff(v * 0.70710678118654752f));
                if (c_raw && f32) ((float*)C)[idx] = v;
                else              ((u16*)C)[idx] = f2bf(v);
            }
        }
    }
}

// ---------------------------------------------------------------------------
extern "C" void kernel_launch(void* const* d_in, const int* in_sizes, int n_in,
                              void* d_out, int out_size, void* d_ws, size_t ws_size,
                              hipStream_t stream) {
    const void* x    = d_in[0];   // (4,4096,1024)  fp32 or bf16
    const void* n1w  = d_in[1];   // (1024,)
    const void* n2w  = d_in[2];   // (1024,)
    const void* w_in = d_in[3];   // (2048,1024)
    const void* w_o  = d_in[4];   // (1024,1024)
    const void* w_mi = d_in[5];   // (2048,1024)
    const void* w_mo = d_in[6];   // (1024,2048)
    // d_in[7] fixed_filter: exp(-0.1*t) geometric -> IIR scan, unused

    char* ws = (char*)d_ws;
    int* flag  = (int*)(ws + 0);                 // 256 B reserved
    u16* wq_in = (u16*)(ws + 256);               // 4 MB
    u16* wq_o  = (u16*)(ws + 256 + 4194304);     // 2 MB
    u16* wq_mi = (u16*)(ws + 256 + 6291456);     // 4 MB
    u16* wq_mo = (u16*)(ws + 256 + 10485760);    // 4 MB
    u16* hbuf  = (u16*)(ws + 256 + 14680064);    // 32 MB (h / h2, bf16)
    u16* qkv   = (u16*)(ws + 256 + 48234496);    // 64 MB (qkv / m, bf16)
    u16* x2b   = (u16*)(ws + 256 + 115343360);   // 32 MB (x2, bf16)

    detect_dtype<<<1, 256, 0, stream>>>((const u16*)x, flag);

    quant_rows<<<2048, 256, 0, stream>>>(w_in, wq_in, 1024, flag);
    quant_rows<<<1024, 256, 0, stream>>>(w_o,  wq_o,  1024, flag);
    quant_rows<<<2048, 256, 0, stream>>>(w_mi, wq_mi, 1024, flag);
    quant_rows<<<1024, 256, 0, stream>>>(w_mo, wq_mo, 2048, flag);

    // h = rmsnorm(x, n1w)
    rmsnorm_k<1><<<16384, 256, 0, stream>>>(x, n1w, hbuf, flag);
    // qkv = h @ wq_in^T   (16384 x 2048)
    gemm_bt<0><<<2048, 256, 0, stream>>>(hbuf, 1024, wq_in,
                                         nullptr, 0, qkv, 0,
                                         16384, 2048, 1024, flag);
    // gate half of qkv <- causal-conv(signal) * silu(gate), in place
    scan_silu<<<dim3(4, 16, 4), 256, 0, stream>>>(qkv);
    // x2 = x + attn @ wq_o^T   (attn = qkv gate half, lda=2048)
    gemm_bt<1><<<1024, 256, 0, stream>>>(qkv + 1024, 2048, wq_o,
                                         x, 1, x2b, 0,
                                         16384, 1024, 1024, flag);
    // h2 = rmsnorm(x2, n2w)
    rmsnorm_k<0><<<16384, 256, 0, stream>>>(x2b, n2w, hbuf, flag);
    // m = gelu(h2 @ wq_mi^T)  (16384 x 2048), overwrite qkv
    gemm_bt<2><<<2048, 256, 0, stream>>>(hbuf, 1024, wq_mi,
                                         nullptr, 0, qkv, 0,
                                         16384, 2048, 1024, flag);
    // out = x2 + m @ wq_mo^T  -> d_out in the detected dtype
    gemm_bt<1><<<1024, 256, 0, stream>>>(qkv, 2048, wq_mo,
                                         x2b, 0, d_out, 1,
                                         16384, 1024, 2048, flag);
}

// Round 5
// 661.566 us; speedup vs baseline: 1.2086x; 1.0184x over previous
//
#include <hip/hip_runtime.h>

typedef unsigned short u16;
typedef __attribute__((ext_vector_type(8))) short s16x8;
typedef __attribute__((ext_vector_type(4))) float f32x4;

#define BM 128
#define BN 128

__device__ __forceinline__ float bf2f(u16 u) {
    union { unsigned int u; float f; } v; v.u = ((unsigned int)u) << 16; return v.f;
}
__device__ __forceinline__ u16 f2bf(float f) {
    union { float f; unsigned int u; } v; v.f = f;
    unsigned int r = v.u + 0x7FFFu + ((v.u >> 16) & 1u);
    return (u16)(r >> 16);
}

// async 16B/lane global->LDS copy. lds base must be wave-uniform; HW writes
// lane l's 16 bytes at base + l*16.
__device__ __forceinline__ void async16(const u16* g, u16* l) {
    __builtin_amdgcn_global_load_lds(
        (const __attribute__((address_space(1))) void*)g,
        (__attribute__((address_space(3))) void*)l,
        16, 0, 0);
}

// ---------------------------------------------------------------------------
// Detect input dtype. flag=1 -> fp32 inputs, flag=0 -> bf16 inputs.
// ---------------------------------------------------------------------------
__global__ __launch_bounds__(256) void detect_dtype(const u16* __restrict__ x,
                                                    int* __restrict__ flag) {
    const int t = threadIdx.x;
    float mx = 0.f;
    #pragma unroll
    for (int j = 0; j < 16; ++j) mx = fmaxf(mx, fabsf(bf2f(x[t * 16 + j])));
    #pragma unroll
    for (int off = 32; off; off >>= 1) mx = fmaxf(mx, __shfl_down(mx, off));
    __shared__ float red[4];
    const int lane = t & 63, wave = t >> 6;
    if (lane == 0) red[wave] = mx;
    __syncthreads();
    if (t == 0) {
        float m = fmaxf(fmaxf(red[0], red[1]), fmaxf(red[2], red[3]));
        *flag = (m > 1e4f) ? 1 : 0;
    }
}

__device__ __forceinline__ float load_raw(const void* p, size_t i, int f32) {
    return f32 ? ((const float*)p)[i] : bf2f(((const u16*)p)[i]);
}

// ---------------------------------------------------------------------------
// Per-row int8 fake-quantization from RAW weights -> canonical bf16.
// ---------------------------------------------------------------------------
__global__ __launch_bounds__(256) void quant_rows(const void* __restrict__ w,
                                                  u16* __restrict__ wq, int L,
                                                  const int* __restrict__ flagp) {
    const int f32 = *flagp;
    const int row = blockIdx.x;
    const int t = threadIdx.x;
    const size_t base = (size_t)row * L;
    float mx = 0.f;
    for (int i = t; i < L; i += 256) mx = fmaxf(mx, fabsf(load_raw(w, base + i, f32)));
    #pragma unroll
    for (int off = 32; off; off >>= 1) mx = fmaxf(mx, __shfl_down(mx, off));
    __shared__ float red[4];
    __shared__ float s_scale;
    const int lane = t & 63, wave = t >> 6;
    if (lane == 0) red[wave] = mx;
    __syncthreads();
    if (t == 0) {
        float m = fmaxf(fmaxf(red[0], red[1]), fmaxf(red[2], red[3]));
        s_scale = fmaxf(m / 127.f, 1e-8f);
    }
    __syncthreads();
    const float scale = s_scale;
    for (int i = t; i < L; i += 256) {
        float v = load_raw(w, base + i, f32);
        wq[base + i] = f2bf(rintf(v / scale) * scale);
    }
}

// ---------------------------------------------------------------------------
// RMSNorm over rows of length 1024 (256 threads x 4 elems).
// ---------------------------------------------------------------------------
template <int IN_RAW>
__global__ __launch_bounds__(256) void rmsnorm_k(const void* __restrict__ x,
                                                 const void* __restrict__ w,
                                                 u16* __restrict__ out,
                                                 const int* __restrict__ flagp) {
    const int f32 = *flagp;
    const int row = blockIdx.x;
    const int t = threadIdx.x;
    float x0, x1, x2, x3;
    if (IN_RAW && f32) {
        float4 xv = ((const float4*)x)[(size_t)row * 256 + t];
        x0 = xv.x; x1 = xv.y; x2 = xv.z; x3 = xv.w;
    } else {
        ushort4 xv = *(const ushort4*)((const u16*)x + (size_t)row * 1024 + t * 4);
        x0 = bf2f(xv.x); x1 = bf2f(xv.y); x2 = bf2f(xv.z); x3 = bf2f(xv.w);
    }
    float s = x0 * x0 + x1 * x1 + x2 * x2 + x3 * x3;
    #pragma unroll
    for (int off = 32; off; off >>= 1) s += __shfl_down(s, off);
    __shared__ float red[4];
    __shared__ float s_rs;
    const int lane = t & 63, wave = t >> 6;
    if (lane == 0) red[wave] = s;
    __syncthreads();
    if (t == 0) {
        float tot = red[0] + red[1] + red[2] + red[3];
        s_rs = 1.0f / sqrtf(tot * (1.0f / 1024.0f) + 1e-6f);
    }
    __syncthreads();
    const float rs = s_rs;
    float w0, w1, w2, w3;
    if (f32) {
        float4 wv = ((const float4*)w)[t];
        w0 = wv.x; w1 = wv.y; w2 = wv.z; w3 = wv.w;
    } else {
        ushort4 wv = *(const ushort4*)((const u16*)w + t * 4);
        w0 = bf2f(wv.x); w1 = bf2f(wv.y); w2 = bf2f(wv.z); w3 = bf2f(wv.w);
    }
    ushort4 o;
    o.x = f2bf(bf2f(f2bf(x0 * rs)) * w0);
    o.y = f2bf(bf2f(f2bf(x1 * rs)) * w1);
    o.z = f2bf(bf2f(f2bf(x2 * rs)) * w2);
    o.w = f2bf(bf2f(f2bf(x3 * rs)) * w3);
    *(ushort4*)(out + (size_t)row * 1024 + t * 4) = o;
}

// ---------------------------------------------------------------------------
// Causal geometric-filter scan + SiLU gate, in-place into the gate half.
// ---------------------------------------------------------------------------
__global__ __launch_bounds__(256) void scan_silu(u16* __restrict__ qkv) {
    const int c = blockIdx.x * 256 + threadIdx.x;   // 0..1023
    const int chunk = blockIdx.y;                   // 0..15
    const int b = blockIdx.z;                       // 0..3
    const int t0 = chunk * 256;
    const int ts = (t0 >= 256) ? (t0 - 256) : 0;    // r^256 ~ 7e-12
    const float r = 0.90483741803595957f;           // exp(-0.1)
    const size_t base = (size_t)b * 4096 * 2048 + c;
    float y = 0.f;
    for (int tt = ts; tt < t0; ++tt) {
        y = y * r + bf2f(qkv[base + (size_t)tt * 2048]);
    }
    for (int tt = t0; tt < t0 + 256; ++tt) {
        const size_t idx = base + (size_t)tt * 2048;
        y = y * r + bf2f(qkv[idx]);
        float g = bf2f(qkv[idx + 1024]);
        float sg = g / (1.f + expf(-g));
        qkv[idx + 1024] = f2bf(y * sg);
    }
}

// ---------------------------------------------------------------------------
// bf16 MFMA GEMM: C(MxN) = A(MxK,lda) @ B(NxK)^T  [+ epilogue]
// EPI: 0 = none, 1 = add RES, 2 = exact GELU
// Double-buffered async staging (BK=32 slices, prefetch issued right after
// the barrier so the next barrier's vmcnt drain is ~free), XOR bank-swizzle
// folded into the per-lane GLOBAL staging offset (LDS slot c of row r holds
// k-chunk c ^ ((r>>1)&3); readers address chunk quad ^ ((lr>>1)&3)) -> 2-way
// LDS access = free. XCD-aware block swizzle keeps B L2-resident.
// ---------------------------------------------------------------------------
template <int EPI>
__global__ __launch_bounds__(256) void gemm_bt(const u16* __restrict__ A, int lda,
                                               const u16* __restrict__ B,
                                               const void* __restrict__ RES, int res_raw,
                                               void* __restrict__ C, int c_raw,
                                               int M, int N, int K,
                                               const int* __restrict__ flagp) {
    const int f32 = *flagp;
    __shared__ u16 As[2][BM * 32];
    __shared__ u16 Bs[2][BN * 32];
    const int t = threadIdx.x;
    const int lane = t & 63, wave = t >> 6;
    const int wm = wave >> 1, wn = wave & 1;
    const int lr = lane & 15, quad = lane >> 4;

    // XCD-aware swizzle: d%8 -> XCD (dispatch round-robin heuristic).
    const int NT = N >> 7;                  // n-tiles
    const int d = blockIdx.x;
    const int xcd = d & 7;
    const int s = d >> 3;
    const int m0 = ((s / NT) * 8 + xcd) * BM;
    const int n0 = (s % NT) * BN;

    // staging: wave w, lane l stages row w*16+(l>>2) (and +64), k-chunk
    // swizzled: global chunk (l&3) ^ ((l>>3)&3), 8 elems. LDS dst uniform.
    const int srow = wave * 16 + (lane >> 2);
    const int scol = ((lane & 3) ^ ((lane >> 3) & 3)) * 8;
    const u16* Ag0 = A + (size_t)(m0 + srow) * lda + scol;
    const u16* Ag1 = A + (size_t)(m0 + srow + 64) * lda + scol;
    const u16* Bg0 = B + (size_t)(n0 + srow) * K + scol;
    const u16* Bg1 = B + (size_t)(n0 + srow + 64) * K + scol;
    u16* Ad0 = &As[0][(wave * 16) * 32];
    u16* Bd0 = &Bs[0][(wave * 16) * 32];
    u16* Ad1 = &As[1][(wave * 16) * 32];
    u16* Bd1 = &Bs[1][(wave * 16) * 32];

    // reader addresses (loop-invariant): chunk = quad ^ ((lr>>1)&3)
    const int rchunk = (quad ^ ((lr >> 1) & 3)) * 8;
    const int a_rd = (wm * 64 + lr) * 32 + rchunk;   // + i*512
    const int b_rd = (wn * 64 + lr) * 32 + rchunk;   // + j*512

    f32x4 acc[4][4];
    #pragma unroll
    for (int i = 0; i < 4; ++i)
        #pragma unroll
        for (int j = 0; j < 4; ++j) acc[i][j] = (f32x4){0.f, 0.f, 0.f, 0.f};

    // prologue: stage slice 0 into buffer 0
    async16(Ag0, Ad0);
    async16(Ag1, Ad0 + 64 * 32);
    async16(Bg0, Bd0);
    async16(Bg1, Bd0 + 64 * 32);

    for (int k0 = 0; k0 < K; k0 += 32) {
        const int cur = (k0 >> 5) & 1;
        __syncthreads();   // drains staging of buf[cur]; prev reads done
        if (k0 + 32 < K) { // prefetch next slice into the other buffer
            if (cur == 0) {
                async16(Ag0 + k0 + 32, Ad1);
                async16(Ag1 + k0 + 32, Ad1 + 64 * 32);
                async16(Bg0 + k0 + 32, Bd1);
                async16(Bg1 + k0 + 32, Bd1 + 64 * 32);
            } else {
                async16(Ag0 + k0 + 32, Ad0);
                async16(Ag1 + k0 + 32, Ad0 + 64 * 32);
                async16(Bg0 + k0 + 32, Bd0);
                async16(Bg1 + k0 + 32, Bd0 + 64 * 32);
            }
        }
        const u16* Asl = As[cur];
        const u16* Bsl = Bs[cur];
        s16x8 af[4], bfr[4];
        #pragma unroll
        for (int i = 0; i < 4; ++i)
            af[i] = *(const s16x8*)&Asl[a_rd + i * 512];
        #pragma unroll
        for (int j = 0; j < 4; ++j)
            bfr[j] = *(const s16x8*)&Bsl[b_rd + j * 512];
        #pragma unroll
        for (int i = 0; i < 4; ++i)
            #pragma unroll
            for (int j = 0; j < 4; ++j)
                acc[i][j] = __builtin_amdgcn_mfma_f32_16x16x32_bf16(
                    af[i], bfr[j], acc[i][j], 0, 0, 0);
    }

    // epilogue: C/D layout col=lane&15, row=quad*4+reg
    #pragma unroll
    for (int i = 0; i < 4; ++i) {
        #pragma unroll
        for (int j = 0; j < 4; ++j) {
            #pragma unroll
            for (int r = 0; r < 4; ++r) {
                int gm = m0 + wm * 64 + i * 16 + quad * 4 + r;
                int gn = n0 + wn * 64 + j * 16 + lr;
                size_t idx = (size_t)gm * N + gn;
                float v = acc[i][j][r];
                if (EPI == 1) {
                    float rv = (res_raw && f32) ? ((const float*)RES)[idx]
                                                : bf2f(((const u16*)RES)[idx]);
                    v += rv;
                }
                if (EPI == 2) v = 0.5f * v * (1.0f + erff(v * 0.70710678118654752f));
                if (c_raw && f32) ((float*)C)[idx] = v;
                else              ((u16*)C)[idx] = f2bf(v);
            }
        }
    }
}

// ---------------------------------------------------------------------------
extern "C" void kernel_launch(void* const* d_in, const int* in_sizes, int n_in,
                              void* d_out, int out_size, void* d_ws, size_t ws_size,
                              hipStream_t stream) {
    const void* x    = d_in[0];   // (4,4096,1024)  fp32 or bf16
    const void* n1w  = d_in[1];   // (1024,)
    const void* n2w  = d_in[2];   // (1024,)
    const void* w_in = d_in[3];   // (2048,1024)
    const void* w_o  = d_in[4];   // (1024,1024)
    const void* w_mi = d_in[5];   // (2048,1024)
    const void* w_mo = d_in[6];   // (1024,2048)
    // d_in[7] fixed_filter: exp(-0.1*t) geometric -> IIR scan, unused

    char* ws = (char*)d_ws;
    int* flag  = (int*)(ws + 0);                 // 256 B reserved
    u16* wq_in = (u16*)(ws + 256);               // 4 MB
    u16* wq_o  = (u16*)(ws + 256 + 4194304);     // 2 MB
    u16* wq_mi = (u16*)(ws + 256 + 6291456);     // 4 MB
    u16* wq_mo = (u16*)(ws + 256 + 10485760);    // 4 MB
    u16* hbuf  = (u16*)(ws + 256 + 14680064);    // 32 MB (h / h2, bf16)
    u16* qkv   = (u16*)(ws + 256 + 48234496);    // 64 MB (qkv / m, bf16)
    u16* x2b   = (u16*)(ws + 256 + 115343360);   // 32 MB (x2, bf16)

    detect_dtype<<<1, 256, 0, stream>>>((const u16*)x, flag);

    quant_rows<<<2048, 256, 0, stream>>>(w_in, wq_in, 1024, flag);
    quant_rows<<<1024, 256, 0, stream>>>(w_o,  wq_o,  1024, flag);
    quant_rows<<<2048, 256, 0, stream>>>(w_mi, wq_mi, 1024, flag);
    quant_rows<<<1024, 256, 0, stream>>>(w_mo, wq_mo, 2048, flag);

    // h = rmsnorm(x, n1w)
    rmsnorm_k<1><<<16384, 256, 0, stream>>>(x, n1w, hbuf, flag);
    // qkv = h @ wq_in^T   (16384 x 2048)
    gemm_bt<0><<<2048, 256, 0, stream>>>(hbuf, 1024, wq_in,
                                         nullptr, 0, qkv, 0,
                                         16384, 2048, 1024, flag);
    // gate half of qkv <- causal-conv(signal) * silu(gate), in place
    scan_silu<<<dim3(4, 16, 4), 256, 0, stream>>>(qkv);
    // x2 = x + attn @ wq_o^T   (attn = qkv gate half, lda=2048)
    gemm_bt<1><<<1024, 256, 0, stream>>>(qkv + 1024, 2048, wq_o,
                                         x, 1, x2b, 0,
                                         16384, 1024, 1024, flag);
    // h2 = rmsnorm(x2, n2w)
    rmsnorm_k<0><<<16384, 256, 0, stream>>>(x2b, n2w, hbuf, flag);
    // m = gelu(h2 @ wq_mi^T)  (16384 x 2048), overwrite qkv
    gemm_bt<2><<<2048, 256, 0, stream>>>(hbuf, 1024, wq_mi,
                                         nullptr, 0, qkv, 0,
                                         16384, 2048, 1024, flag);
    // out = x2 + m @ wq_mo^T  -> d_out in the detected dtype
    gemm_bt<1><<<1024, 256, 0, stream>>>(qkv, 2048, wq_mo,
                                         x2b, 0, d_out, 1,
                                         16384, 1024, 2048, flag);
}